// Round 14
// baseline (15014.485 us; speedup 1.0000x reference)
//
#include <hip/hip_runtime.h>

// PositionCloser round 14: R9 shell (compute+loss wave pair, 2048 waves =
// 2/SIMD, LDS h-ring + chunk flags) with the matvec moved to the IDLE MFMA
// pipe (R5 core, correctness-proven). VALU-dot plateau is ~1037 busy cy/step
// (R9/R13, allocator AGPR tax irremovable at source level); MFMA co-issues
// with VALU (m114). R5's per-gate MFMA->bperm serialization is fixed: all 32
// MFMA first (16 independent 2-chains), then all 16 bpermute-outs in one
// latency window.

#define CH  128
#define HID 64

typedef __fp16 f16x8 __attribute__((ext_vector_type(8)));
typedef float  f32x4 __attribute__((ext_vector_type(4)));
typedef int    i32x4 __attribute__((ext_vector_type(4)));

#define MFMA16(a, b, c) __builtin_amdgcn_mfma_f32_16x16x32_f16((a), (b), (c), 0, 0, 0)

__device__ __forceinline__ float rlf(float v, int l) {
  return __builtin_bit_cast(float, __builtin_amdgcn_readlane(__builtin_bit_cast(int, v), l));
}
__device__ __forceinline__ int packh(float a, float b) {
  return __builtin_bit_cast(int, __builtin_amdgcn_cvt_pkrtz(a, b));
}
__device__ __forceinline__ int bperm(int byteaddr, int src) {
  return __builtin_amdgcn_ds_bpermute(byteaddr, src);
}
__device__ __forceinline__ float bpermf(int byteaddr, float src) {
  return __builtin_bit_cast(float,
      __builtin_amdgcn_ds_bpermute(byteaddr, __builtin_bit_cast(int, src)));
}
__device__ __forceinline__ float frcp(float x) { return __builtin_amdgcn_rcpf(x); }
__device__ __forceinline__ float sigm(float x) { return frcp(1.0f + __expf(-x)); }
__device__ __forceinline__ float tanh_(float x) {
  float e = __expf(2.0f * x);
  return 1.0f - 2.0f * frcp(e + 1.0f);
}
template <int CTRL, int RMASK>
__device__ __forceinline__ float dpp_add(float v) {
  int x = __builtin_amdgcn_update_dpp(0, __builtin_bit_cast(int, v), CTRL, RMASK, 0xF, true);
  return v + __builtin_bit_cast(float, x);
}
__device__ __forceinline__ float dpp_xor1(float v) {  // quad_perm [1,0,3,2]
  int x = __builtin_amdgcn_update_dpp(0, __builtin_bit_cast(int, v), 0xB1, 0xF, 0xF, true);
  return __builtin_bit_cast(float, x);
}
__device__ __forceinline__ float dpp_wave_sum(float v) {  // total lands in lane 63
  v = dpp_add<0x111, 0xF>(v);
  v = dpp_add<0x112, 0xF>(v);
  v = dpp_add<0x114, 0xF>(v);
  v = dpp_add<0x118, 0xF>(v);
  v = dpp_add<0x142, 0xA>(v);   // row_bcast:15
  v = dpp_add<0x143, 0xC>(v);   // row_bcast:31
  return v;
}

__global__ __launch_bounds__(128)
void pc_lstm_kernel(const int* __restrict__ inds,
                    const float* __restrict__ p,
                    const float* __restrict__ ls_probs,
                    const float* __restrict__ open_probs,
                    const int* __restrict__ open_slices,
                    const float* __restrict__ open_hx,
                    const float* __restrict__ W_ih,
                    const float* __restrict__ W_hh,
                    const float* __restrict__ b_ih,
                    const float* __restrict__ b_hh,
                    const float* __restrict__ W_out,
                    const float* __restrict__ b_out,
                    const int* __restrict__ n_chunks_p,
                    float* __restrict__ out)
{
  __shared__ __fp16 ring[2][CH][HID];   // 32 KB: h history for the lagged loss
  __shared__ int prod;                  // chunks fully written by wave0
  __shared__ int cons;                  // chunks fully consumed by wave1

  const int tid  = threadIdx.x;
  const int wv   = tid >> 6;           // 0 = compute (MFMA), 1 = loss
  const int lane = tid & 63;
  const int s    = blockIdx.x;         // one sequence per block
  const int n_chunks = n_chunks_p[0];
  const int tbase = inds[s >> 4] + (s & 15);
  const float2* p2 = (const float2*)p;

  if (tid == 0) { prod = 0; cons = 0; }
  __syncthreads();                      // only barrier in the kernel

  if (wv == 0) {
    // ================= compute wave (MFMA matvec) =================
    const int q  = lane >> 4;
    const int lm = lane & 15;

    // B fragments (R5-verified): B[k][n]: n=lm -> W_hh row g*64+16cb+lm,
    // k = 32*kh + 8*q + j -> W_hh col. 32 frags = 128 words (AGPR-friendly:
    // MFMA reads AGPR operands natively -> no per-use move tax).
    f16x8 Bf[4][4][2];
#pragma unroll
    for (int g = 0; g < 4; ++g)
#pragma unroll
      for (int cb = 0; cb < 4; ++cb)
#pragma unroll
        for (int kh = 0; kh < 2; ++kh) {
          const float* src = W_hh + (g * HID + 16 * cb + lm) * HID + 32 * kh + 8 * q;
          f16x8 b;
#pragma unroll
          for (int j = 0; j < 8; ++j) b[j] = (__fp16)src[j];
          Bf[g][cb][kh] = b;
        }

    // per-lane (lane = hid) gate constants
    float wxa[4], wxb[4], bb[4];
#pragma unroll
    for (int g = 0; g < 4; ++g) {
      const int r = g * HID + lane;
      wxa[g] = W_ih[2 * r];
      wxb[g] = W_ih[2 * r + 1];
      bb[g]  = b_ih[r] + b_hh[r];
    }
    float h = open_hx[(s * 2 + 0) * HID + lane];
    float c = open_hx[(s * 2 + 1) * HID + lane];

    // bpermute byte addresses (loop-invariant; R5-verified layout)
    int aadr0[4], aadr1[4];
#pragma unroll
    for (int m = 0; m < 4; ++m) {
      aadr0[m] = 8 * (4 * q + m);        // h pair (8q+2m, 8q+2m+1), K-half 0
      aadr1[m] = 8 * (16 + 4 * q + m);   // K-half 1
    }
    const int dadr = 4 * lm;             // D redistribute: pull from lane lm

    float2 curA = p2[tbase + lane];
    float2 curB = p2[tbase + HID + lane];
    float2 nxtA = curA, nxtB = curB;

    for (int off = 0; off < n_chunks; ++off) {
      if (off) { curA = nxtA; curB = nxtB; }
      const float px0 = rlf(curA.x, 0);
      const float px1 = rlf(curA.y, 0);
      float2 xA, xB;                       // pre-subtracted chunk base
      xA.x = curA.x - px0; xA.y = curA.y - px1;
      xB.x = curB.x - px0; xB.y = curB.y - px1;
      if (off + 1 < n_chunks) {
        const int nb = tbase + (off + 1) * CH;
        nxtA = p2[nb + lane];
        nxtB = p2[nb + HID + lane];
      }
      while (__hip_atomic_load(&cons, __ATOMIC_ACQUIRE, __HIP_MEMORY_SCOPE_WORKGROUP) + 2 <= off)
        __builtin_amdgcn_s_sleep(8);

      __fp16* slot = &ring[off & 1][0][0];
#pragma unroll
      for (int hf = 0; hf < 2; ++hf) {
        const float xcx = hf ? xB.x : xA.x;
        const float xcy = hf ? xB.y : xA.y;
#pragma unroll 1
        for (int tl = 0; tl < 64; ++tl) {
          // ---- A operand: replicated-row h pairs (8 independent bpermutes)
          const int hp = packh(h, dpp_xor1(h));   // even lane 2j: (h_2j, h_2j+1)
          i32x4 t0, t1;
#pragma unroll
          for (int m = 0; m < 4; ++m) {
            t0[m] = bperm(aadr0[m], hp);
            t1[m] = bperm(aadr1[m], hp);
          }
          const f16x8 a0 = __builtin_bit_cast(f16x8, t0);
          const f16x8 a1 = __builtin_bit_cast(f16x8, t1);

          // ---- ALL 32 MFMA first (16 independent 2-chains; MFMA pipe)
          const f32x4 z4 = {0.0f, 0.0f, 0.0f, 0.0f};
          f32x4 C[4][4];
#pragma unroll
          for (int g = 0; g < 4; ++g)
#pragma unroll
            for (int cb = 0; cb < 4; ++cb) {
              f32x4 acc = MFMA16(a0, Bf[g][cb][0], z4);
              C[g][cb] = MFMA16(a1, Bf[g][cb][1], acc);
            }

          // ---- x-contribution (independent; fills the MFMA window)
          const float x0 = rlf(xcx, tl);
          const float x1 = rlf(xcy, tl);
          float xg[4];
#pragma unroll
          for (int g = 0; g < 4; ++g)
            xg[g] = fmaf(x1, wxb[g], fmaf(x0, wxa[g], bb[g]));

          // ---- ALL 16 bpermute-outs in one latency window
          float r[4][4];
#pragma unroll
          for (int g = 0; g < 4; ++g)
#pragma unroll
            for (int cb = 0; cb < 4; ++cb)
              r[g][cb] = bpermf(dadr, C[g][cb][0]);

          float pre[4];
#pragma unroll
          for (int g = 0; g < 4; ++g)
            pre[g] = ((q == 0) ? r[g][0] : (q == 1) ? r[g][1]
                    : (q == 2) ? r[g][2] : r[g][3]) + xg[g];

          const float ig = sigm(pre[0]);
          const float fg = sigm(pre[1]);
          const float gg = tanh_(pre[2]);
          const float og = sigm(pre[3]);
          c = fmaf(fg, c, ig * gg);
          h = og * tanh_(c);

          slot[(hf * 64 + tl) * HID + lane] = (__fp16)h;   // ds_write_b16
        }
      }
      if (lane == 0)
        __hip_atomic_store(&prod, off + 1, __ATOMIC_RELEASE, __HIP_MEMORY_SCOPE_WORKGROUP);
    }
  } else {
    // ================= loss wave (R9 verbatim) =================
    const float wo   = W_out[lane];
    const float bout = b_out[0];
    const int   os   = open_slices[s];
    const float OL   = __logf(p[2 * os]) + __logf(p[2 * os + 1]);
    const float coef = open_probs[s] * (2.0f * ls_probs[s] - 1.0f);

    float S = 1.0f, D = 1.0f, lsum = 0.0f, psum = 0.0f;

    for (int off = 0; off < n_chunks; ++off) {
      const int cb = tbase + off * CH;
      const float2 cA = p2[cb + lane];
      const float2 cB = p2[cb + HID + lane];
      const float LA = __logf(cA.x) + __logf(cA.y);
      const float LB = __logf(cB.x) + __logf(cB.y);

      while (__hip_atomic_load(&prod, __ATOMIC_ACQUIRE, __HIP_MEMORY_SCOPE_WORKGROUP) <= off)
        __builtin_amdgcn_s_sleep(32);

      const __fp16* slot = &ring[off & 1][0][0];
#pragma unroll 1
      for (int tt = 0; tt < CH; ++tt) {
        const float hv = (float)slot[tt * HID + lane];
        const float z  = rlf(dpp_wave_sum(hv * wo), 63);
        const float pr = sigm(z + bout);
        const float Lt = (tt < 64) ? rlf(LA, tt) : rlf(LB, tt - 64);
        const float pn = (tt == 0) ? pr : pr * D;
        lsum = fmaf(pn, Lt, lsum);
        psum += pn;
        if (tt == 0)           D = S * (1.0f - pr);   // chunk t=0 undiscounted (ref quirk)
        else if (tt < CH - 1)  D *= (1.0f - pr);
        else                   S = D;                  // carry excludes (1-p_last)
      }
      if (lane == 0)
        __hip_atomic_store(&cons, off + 1, __ATOMIC_RELEASE, __HIP_MEMORY_SCOPE_WORKGROUP);
    }
    if (lane == 0) atomicAdd(out, coef * (lsum - OL * psum));
  }
}

extern "C" void kernel_launch(void* const* d_in, const int* in_sizes, int n_in,
                              void* d_out, int out_size, void* d_ws, size_t ws_size,
                              hipStream_t stream) {
  (void)hipMemsetAsync(d_out, 0, sizeof(float), stream);

  pc_lstm_kernel<<<dim3(1024), dim3(128), 0, stream>>>(
      (const int*)d_in[0],    // inds
      (const float*)d_in[1],  // p
      (const float*)d_in[2],  // ls_probs
      (const float*)d_in[3],  // open_probs
      (const int*)d_in[4],    // open_slices
      (const float*)d_in[5],  // open_hx
      (const float*)d_in[6],  // W_ih
      (const float*)d_in[7],  // W_hh
      (const float*)d_in[8],  // b_ih
      (const float*)d_in[9],  // b_hh
      (const float*)d_in[10], // W_out
      (const float*)d_in[11], // b_out
      (const int*)d_in[12],   // n_chunks
      (float*)d_out);
}